// Round 14
// baseline (201.226 us; speedup 1.0000x reference)
//
#include <hip/hip_runtime.h>

// Problem constants: N=50000 nodes, E=800000 edges, IN_F=H_F=128, OUT_F=3.
#define NN   50000
#define NE   800000
#define FH   128
#define NOUT 3
#define BN_EPS 1e-5f

#define CAP  48            // bucket capacity; in-deg ~ Poisson(16), dataset
                           // max ~40; P(deg>=48) ~ 1e-9/node
#define EWS  65535.0f      // 16-bit fixed-point scale for bucket entries
#define IEWS (1.0f / 65535.0f)
#define FXS  8388608.0f    // 2^23 fixed-point scale for degree accumulation
#define IFXS (1.0f / 8388608.0f)

#define FUSED_BLKS  1564   // even -> gemm (782), odd -> bucket (782)
#define GATHER_BLKS 2048   // persistent; 8192 waves
#define RED_BLKS    (GATHER_BLKS / 256)   // 8

// Workspace layout (float-sized slots). ~9.43M floats = 37.7 MB.
#define WS_H2      0           // h packed bf16x2, uint[NN*64]
#define WS_AGG2    3200000     // relu out packed bf16x2 uint[NN*64]
#define WS_BUCKET  6400000     // uint[NN*CAP] (src<<16 | ew16)  [2400000]
#define WS_PACKED  8800000     // u64[NN]: hi32=count, lo32=fx23 weighted deg
#define WS_PARTIAL 8900000     // float[GATHER_BLKS*256] stats partials
#define WS_STAGE2  9424288     // float[RED_BLKS*256]
#define WS_PREP    9426336     // wmod[128*3], bias_out[3]

typedef __attribute__((ext_vector_type(8))) short  short8;   // 8 bf16
typedef __attribute__((ext_vector_type(4))) float  f32x4;

// round-to-nearest-even bf16 helpers
__device__ __forceinline__ unsigned int pack_bf16(float a, float b) {
    unsigned int ua = __float_as_uint(a);
    unsigned int ub = __float_as_uint(b);
    ua += 0x7fffu + ((ua >> 16) & 1u);
    ub += 0x7fffu + ((ub >> 16) & 1u);
    return (ua >> 16) | (ub & 0xffff0000u);
}
__device__ __forceinline__ unsigned short bf16_1(float a) {
    unsigned int ua = __float_as_uint(a);
    ua += 0x7fffu + ((ua >> 16) & 1u);
    return (unsigned short)(ua >> 16);
}
__device__ __forceinline__ float bf16_lo(unsigned int u) {
    return __uint_as_float(u << 16);
}
__device__ __forceinline__ float bf16_hi(unsigned int u) {
    return __uint_as_float(u & 0xffff0000u);
}

// ---------------------------------------------------------------------------
// K1: FUSED MFMA-gemm + bucket, 1:1 interleaved (even block -> gemm, odd ->
// bucket). The two halves occupy DISJOINT pipes: gemm = MFMA + LDS, bucket =
// fabric atomics (r7/8 failed because the VALU gemm competed for issue; the
// MFMA gemm doesn't). No ordering dependency: gemm no longer reads packed
// (dinv is computed on-the-fly in gather).
// ---------------------------------------------------------------------------
__global__ __launch_bounds__(256) void k_gemm_bucket(
        const float* __restrict__ x, const float* __restrict__ w,
        unsigned int* __restrict__ h2,
        const int* __restrict__ ei, const float* __restrict__ ew,
        unsigned long long* __restrict__ packed,
        unsigned int* __restrict__ bucket) {
    __shared__ unsigned short swB[32 * 64 * 8];  // 32 KB (gemm half only)
    const int tid = threadIdx.x;

    if ((blockIdx.x & 1) == 0) {
        const int gblk = blockIdx.x >> 1;  // 0..781
        // stage B fragments: fs=kc*8+t; lane l elem j <- w[kc*32+(l>>4)*8+j][16t+(l&15)]
#pragma unroll
        for (int it = 0; it < 8; ++it) {
            int s  = tid + it * 256;
            int l  = s & 63;
            int fs = s >> 6;
            int kc = fs >> 3, t = fs & 7;
            int n  = (l & 15) + 16 * t;
            int k0 = kc * 32 + (l >> 4) * 8;
            unsigned short* dst = &swB[s * 8];
#pragma unroll
            for (int j = 0; j < 8; ++j)
                dst[j] = bf16_1(w[(size_t)(k0 + j) * FH + n]);
        }
        __syncthreads();

        const int wv = tid >> 6, l = tid & 63;
        const int m = l & 15, q = l >> 4;
        int node = gblk * 64 + wv * 16 + m;
        if (node >= NN) node = NN - 1;           // clamp loads; stores guarded

        f32x4 acc[8];
#pragma unroll
        for (int t = 0; t < 8; ++t) acc[t] = (f32x4){0.f, 0.f, 0.f, 0.f};

#pragma unroll
        for (int kc = 0; kc < 4; ++kc) {
            const float* xr = x + (size_t)node * FH + kc * 32 + q * 8;
            float4 a0 = *(const float4*)xr;
            float4 a1 = *(const float4*)(xr + 4);
            union { short8 s8; uint4 u4; } af;
            af.u4.x = pack_bf16(a0.x, a0.y);  af.u4.y = pack_bf16(a0.z, a0.w);
            af.u4.z = pack_bf16(a1.x, a1.y);  af.u4.w = pack_bf16(a1.z, a1.w);
#pragma unroll
            for (int t = 0; t < 8; ++t) {
                union { short8 s8; uint4 u4; } bf;
                bf.u4 = *(const uint4*)&swB[((kc * 8 + t) * 64 + l) * 8];
                acc[t] = __builtin_amdgcn_mfma_f32_16x16x32_bf16(af.s8, bf.s8, acc[t], 0, 0, 0);
            }
        }

        // epilogue: D -> LDS (reuse swB) -> coalesced global
        __syncthreads();
        unsigned short* sc = swB;  // 64 nodes x 128 feats bf16 = 16 KB
#pragma unroll
        for (int t = 0; t < 8; ++t) {
#pragma unroll
            for (int r = 0; r < 4; ++r) {
                int ml = wv * 16 + q * 4 + r;
                int f  = t * 16 + m;
                sc[ml * FH + f] = bf16_1(acc[t][r]);
            }
        }
        __syncthreads();
        const uint4* s4 = (const uint4*)sc;
#pragma unroll
        for (int i = 0; i < 4; ++i) {
            int u  = tid + i * 256;
            int nl = u >> 4;
            int ng = gblk * 64 + nl;
            if (ng < NN)
                *((uint4*)h2 + (size_t)ng * 16 + (u & 15)) = s4[u];
        }
    } else {
        // bucket half: 4 edges/thread, separated phases.
        const int bidx = blockIdx.x >> 1;             // 0..781
        const int e0 = bidx * 1024 + tid;
        int                col[4];
        unsigned int       ent[4];
        unsigned long long add[4];
        int                ok[4];
#pragma unroll
        for (int k = 0; k < 4; ++k) {
            int e = e0 + k * 256;
            ok[k] = (e < NE);
            int ee = ok[k] ? e : 0;
            int row = ei[ee];
            col[k] = ei[NE + ee];
            float wv2 = ew[ee];
            ent[k] = ((unsigned int)row << 16) | __float2uint_rn(wv2 * EWS);
            add[k] = (1ULL << 32) | (unsigned long long)__float2uint_rn(wv2 * FXS);
        }
        int slot[4];
#pragma unroll
        for (int k = 0; k < 4; ++k)
            slot[k] = ok[k] ? (int)(atomicAdd(&packed[col[k]], add[k]) >> 32) : 0;
#pragma unroll
        for (int k = 0; k < 4; ++k)
            if (ok[k]) bucket[(size_t)col[k] * CAP + slot[k]] = ent[k];
    }
}

// ---------------------------------------------------------------------------
// K2: persistent gather-aggregate + fused BN-stats. dinv computed on the fly
// from packed (lo32 = fx23 weighted degree; hi32 = count). packed[n] supplies
// both c and dvn in ONE 8-byte load.
// ---------------------------------------------------------------------------
__global__ __launch_bounds__(256) void k_gather(const unsigned int* __restrict__ h2,
                                                const unsigned int* __restrict__ packedlo,
                                                const unsigned long long* __restrict__ packed,
                                                const unsigned int* __restrict__ bucket,
                                                const float* __restrict__ conv_b,
                                                unsigned int* __restrict__ agg2,
                                                float* __restrict__ partial) {
    const int lane = threadIdx.x & 63;
    const int wv   = threadIdx.x >> 6;
    float2 bv = *(const float2*)(conv_b + lane * 2);

    float sa = 0.f, sb = 0.f, sa2 = 0.f, sb2 = 0.f;

    for (int n = blockIdx.x * 4 + wv; n < NN; n += GATHER_BLKS * 4) {
        unsigned long long pk = packed[n];
        int c = (int)(pk >> 32);
        float dvn = rsqrtf((float)(unsigned int)(pk & 0xffffffffu) * IFXS + 1.0f);

        unsigned int hself = h2[(size_t)n * 64 + lane];
        float ax = bf16_lo(hself) * dvn;
        float ay = bf16_hi(hself) * dvn;

        const unsigned int* bkt = bucket + (size_t)n * CAP;
        int j = 0;
        for (; j + 8 <= c; j += 8) {
            uint4 b0 = *(const uint4*)(bkt + j);
            uint4 b1 = *(const uint4*)(bkt + j + 4);
            unsigned int u[8] = {b0.x, b0.y, b0.z, b0.w, b1.x, b1.y, b1.z, b1.w};
            float t[8];
            unsigned int q[8];
#pragma unroll
            for (int r = 0; r < 8; ++r) {
                int s = u[r] >> 16;
                float ds = rsqrtf((float)packedlo[2 * s] * IFXS + 1.0f);
                t[r] = ds * (float)(u[r] & 0xffffu) * IEWS;
                q[r] = h2[(size_t)s * 64 + lane];
            }
#pragma unroll
            for (int r = 0; r < 8; ++r) {
                ax = fmaf(bf16_lo(q[r]), t[r], ax);
                ay = fmaf(bf16_hi(q[r]), t[r], ay);
            }
        }
        if (j + 4 <= c) {
            uint4 b0 = *(const uint4*)(bkt + j);
            unsigned int u[4] = {b0.x, b0.y, b0.z, b0.w};
#pragma unroll
            for (int r = 0; r < 4; ++r) {
                int s = u[r] >> 16;
                float ds = rsqrtf((float)packedlo[2 * s] * IFXS + 1.0f);
                float t = ds * (float)(u[r] & 0xffffu) * IEWS;
                unsigned int q = h2[(size_t)s * 64 + lane];
                ax = fmaf(bf16_lo(q), t, ax);
                ay = fmaf(bf16_hi(q), t, ay);
            }
            j += 4;
        }
        for (; j < c; ++j) {
            unsigned int u0 = bkt[j];
            int s0 = u0 >> 16;
            float ds = rsqrtf((float)packedlo[2 * s0] * IFXS + 1.0f);
            float t0 = ds * (float)(u0 & 0xffffu) * IEWS;
            unsigned int q0 = h2[(size_t)s0 * 64 + lane];
            ax = fmaf(bf16_lo(q0), t0, ax);  ay = fmaf(bf16_hi(q0), t0, ay);
        }

        float ox = fmaxf(fmaf(dvn, ax, bv.x), 0.f);
        float oy = fmaxf(fmaf(dvn, ay, bv.y), 0.f);
        agg2[(size_t)n * 64 + lane] = pack_bf16(ox, oy);

        sa += ox;  sa2 = fmaf(ox, ox, sa2);
        sb += oy;  sb2 = fmaf(oy, oy, sb2);
    }

    // block-level stats reduce: partial[b][0..127]=sum, [128..255]=sumsq
    __shared__ float red[256];
    float vals[4] = {sa, sb, sa2, sb2};
    float* pb = partial + (size_t)blockIdx.x * 256;
#pragma unroll
    for (int r = 0; r < 4; ++r) {
        red[threadIdx.x] = vals[r];
        __syncthreads();
        if (wv == 0) {
            float t = red[lane] + red[lane + 64] + red[lane + 128] + red[lane + 192];
            pb[((r < 2) ? 0 : FH) + 2 * lane + (r & 1)] = t;
        }
        __syncthreads();
    }
}

// ---------------------------------------------------------------------------
// K3: stage-2 stats reduction: 8 blocks, each sums 256 partial rows.
// ---------------------------------------------------------------------------
__global__ __launch_bounds__(256) void k_red(const float* __restrict__ partial,
                                             float* __restrict__ stage2) {
    int i = threadIdx.x;
    const float* base = partial + (size_t)blockIdx.x * 256 * 256;
    float acc = 0.f;
    for (int j = 0; j < 256; ++j) acc += base[j * 256 + i];
    stage2[blockIdx.x * 256 + i] = acc;
}

// ---------------------------------------------------------------------------
// K4: final stats reduce + fold BN affine into the linear.
// ---------------------------------------------------------------------------
__global__ void k_prep(const float* __restrict__ stage2,
                       const float* __restrict__ gamma,
                       const float* __restrict__ beta,
                       const float* __restrict__ lin_w,
                       const float* __restrict__ lin_b,
                       float* __restrict__ prep) {
    __shared__ float ssum[256];
    __shared__ float red[3 * FH];
    int i = threadIdx.x;  // 256 threads
    float acc = 0.f;
#pragma unroll
    for (int r = 0; r < RED_BLKS; ++r) acc += stage2[r * 256 + i];
    ssum[i] = acc;
    __syncthreads();
    if (i < FH) {
        float mean = ssum[i] * (1.0f / NN);
        float var  = ssum[FH + i] * (1.0f / NN) - mean * mean;
        float inv  = rsqrtf(var + BN_EPS);
        float sc   = inv * gamma[i];
        float sh   = fmaf(-mean, sc, beta[i]);
#pragma unroll
        for (int o = 0; o < NOUT; ++o) {
            float lw = lin_w[i * NOUT + o];
            prep[i * NOUT + o] = sc * lw;
            red[o * FH + i]    = sh * lw;
        }
    }
    __syncthreads();
    if (i < NOUT) {
        float s = lin_b[i];
        for (int f = 0; f < FH; ++f) s += red[i * FH + f];
        prep[3 * FH + i] = s;
    }
}

// ---------------------------------------------------------------------------
// K5: out[n][o] = sum_f agg[n][f] * wmod[f][o] + bias_out[o]
// ---------------------------------------------------------------------------
__global__ __launch_bounds__(256) void k_final(const unsigned int* __restrict__ agg2,
                                               const float* __restrict__ prep,
                                               float* __restrict__ out) {
    int n = blockIdx.x * 4 + (threadIdx.x >> 6);
    int lane = threadIdx.x & 63;
    int f0 = lane * 2, f1 = lane * 2 + 1;

    unsigned int v = agg2[(size_t)n * 64 + lane];
    float vx = bf16_lo(v), vy = bf16_hi(v);

    float o0 = vx * prep[f0 * NOUT + 0] + vy * prep[f1 * NOUT + 0];
    float o1 = vx * prep[f0 * NOUT + 1] + vy * prep[f1 * NOUT + 1];
    float o2 = vx * prep[f0 * NOUT + 2] + vy * prep[f1 * NOUT + 2];

#pragma unroll
    for (int off = 32; off > 0; off >>= 1) {
        o0 += __shfl_down(o0, off, 64);
        o1 += __shfl_down(o1, off, 64);
        o2 += __shfl_down(o2, off, 64);
    }
    if (lane == 0) {
        out[n * NOUT + 0] = o0 + prep[3 * FH + 0];
        out[n * NOUT + 1] = o1 + prep[3 * FH + 1];
        out[n * NOUT + 2] = o2 + prep[3 * FH + 2];
    }
}

// ---------------------------------------------------------------------------
extern "C" void kernel_launch(void* const* d_in, const int* in_sizes, int n_in,
                              void* d_out, int out_size, void* d_ws, size_t ws_size,
                              hipStream_t stream) {
    const float* x      = (const float*)d_in[0];
    const int*   ei     = (const int*)d_in[1];   // [2][NE] int32
    const float* ew     = (const float*)d_in[2];
    const float* conv_w = (const float*)d_in[3];
    const float* conv_b = (const float*)d_in[4];
    const float* gamma  = (const float*)d_in[5];
    const float* beta   = (const float*)d_in[6];
    const float* lin_w  = (const float*)d_in[7];
    const float* lin_b  = (const float*)d_in[8];
    float* out = (float*)d_out;
    float* ws  = (float*)d_ws;

    unsigned int*       h2      = (unsigned int*)(ws + WS_H2);
    unsigned int*       agg2    = (unsigned int*)(ws + WS_AGG2);
    unsigned int*       bucket  = (unsigned int*)(ws + WS_BUCKET);
    unsigned long long* packed  = (unsigned long long*)(ws + WS_PACKED);
    float*              partial = ws + WS_PARTIAL;
    float*              stage2  = ws + WS_STAGE2;
    float*              prep    = ws + WS_PREP;

    // ws is poisoned 0xAA before every launch — zero the atomic accumulator.
    hipMemsetAsync(packed, 0, (size_t)NN * sizeof(unsigned long long), stream);

    k_gemm_bucket<<<FUSED_BLKS, 256, 0, stream>>>(x, conv_w, h2, ei, ew, packed, bucket);
    k_gather<<<GATHER_BLKS, 256, 0, stream>>>(h2, (const unsigned int*)packed, packed,
                                              bucket, conv_b, agg2, partial);
    k_red   <<<RED_BLKS,    256, 0, stream>>>(partial, stage2);
    k_prep  <<<1,           256, 0, stream>>>(stage2, gamma, beta, lin_w, lin_b, prep);
    k_final <<<NN / 4,      256, 0, stream>>>(agg2, prep, out);
}

// Round 15
// 183.659 us; speedup vs baseline: 1.0956x; 1.0956x over previous
//
#include <hip/hip_runtime.h>

// Problem constants: N=50000 nodes, E=800000 edges, IN_F=H_F=128, OUT_F=3.
#define NN   50000
#define NE   800000
#define FH   128
#define NOUT 3
#define BN_EPS 1e-5f

#define CAP  48            // bucket capacity; in-deg ~ Poisson(16), dataset
                           // max ~40; P(deg>=48) ~ 1e-9/node
#define EWS  65535.0f      // 16-bit fixed-point scale for bucket entries
#define IEWS (1.0f / 65535.0f)
#define FXS  8388608.0f    // 2^23 fixed-point scale for degree accumulation
#define IFXS (1.0f / 8388608.0f)

#define FUSED_BLKS  1564   // even -> gemm (782), odd -> bucket (782)
#define DINV_BLKS   196    // ceil(NN/256)
#define GATHER_BLKS 2048   // persistent; 8192 waves
#define RED_BLKS    (GATHER_BLKS / 256)   // 8

// Workspace layout (float-sized slots). ~9.48M floats = 37.9 MB.
#define WS_H2      0           // h packed bf16x2, uint[NN*64]
#define WS_AGG2    3200000     // relu out packed bf16x2 uint[NN*64]
#define WS_BUCKET  6400000     // uint[NN*CAP] (src<<16 | ew16)  [2400000]
#define WS_PACKED  8800000     // u64[NN]: hi32=count, lo32=fx23 weighted deg
#define WS_DINV    8900000     // float[NN]
#define WS_PARTIAL 8950000     // float[GATHER_BLKS*256] stats partials
#define WS_STAGE2  9474288     // float[RED_BLKS*256]
#define WS_PREP    9476336     // wmod[128*3], bias_out[3]

typedef __attribute__((ext_vector_type(8))) short  short8;   // 8 bf16
typedef __attribute__((ext_vector_type(4))) float  f32x4;

// round-to-nearest-even bf16 helpers
__device__ __forceinline__ unsigned int pack_bf16(float a, float b) {
    unsigned int ua = __float_as_uint(a);
    unsigned int ub = __float_as_uint(b);
    ua += 0x7fffu + ((ua >> 16) & 1u);
    ub += 0x7fffu + ((ub >> 16) & 1u);
    return (ua >> 16) | (ub & 0xffff0000u);
}
__device__ __forceinline__ unsigned short bf16_1(float a) {
    unsigned int ua = __float_as_uint(a);
    ua += 0x7fffu + ((ua >> 16) & 1u);
    return (unsigned short)(ua >> 16);
}
__device__ __forceinline__ float bf16_lo(unsigned int u) {
    return __uint_as_float(u << 16);
}
__device__ __forceinline__ float bf16_hi(unsigned int u) {
    return __uint_as_float(u & 0xffff0000u);
}

// ---------------------------------------------------------------------------
// K1: FUSED MFMA-gemm + bucket, 1:1 interleaved (even block -> gemm, odd ->
// bucket). Disjoint pipes: gemm = MFMA + LDS, bucket = fabric atomics.
// r14 measured: 53.7 us vs 60 us serial -- the MFMA gemm rides nearly free
// under the atomic-bound bucket (MfmaUtil 1.1%, VALUBusy 4.6%).
// ---------------------------------------------------------------------------
__global__ __launch_bounds__(256) void k_gemm_bucket(
        const float* __restrict__ x, const float* __restrict__ w,
        unsigned int* __restrict__ h2,
        const int* __restrict__ ei, const float* __restrict__ ew,
        unsigned long long* __restrict__ packed,
        unsigned int* __restrict__ bucket) {
    __shared__ unsigned short swB[32 * 64 * 8];  // 32 KB (gemm half only)
    const int tid = threadIdx.x;

    if ((blockIdx.x & 1) == 0) {
        const int gblk = blockIdx.x >> 1;  // 0..781
        // stage B fragments: fs=kc*8+t; lane l elem j <- w[kc*32+(l>>4)*8+j][16t+(l&15)]
#pragma unroll
        for (int it = 0; it < 8; ++it) {
            int s  = tid + it * 256;
            int l  = s & 63;
            int fs = s >> 6;
            int kc = fs >> 3, t = fs & 7;
            int n  = (l & 15) + 16 * t;
            int k0 = kc * 32 + (l >> 4) * 8;
            unsigned short* dst = &swB[s * 8];
#pragma unroll
            for (int j = 0; j < 8; ++j)
                dst[j] = bf16_1(w[(size_t)(k0 + j) * FH + n]);
        }
        __syncthreads();

        const int wv = tid >> 6, l = tid & 63;
        const int m = l & 15, q = l >> 4;
        int node = gblk * 64 + wv * 16 + m;
        if (node >= NN) node = NN - 1;           // clamp loads; stores guarded

        f32x4 acc[8];
#pragma unroll
        for (int t = 0; t < 8; ++t) acc[t] = (f32x4){0.f, 0.f, 0.f, 0.f};

#pragma unroll
        for (int kc = 0; kc < 4; ++kc) {
            const float* xr = x + (size_t)node * FH + kc * 32 + q * 8;
            float4 a0 = *(const float4*)xr;
            float4 a1 = *(const float4*)(xr + 4);
            union { short8 s8; uint4 u4; } af;
            af.u4.x = pack_bf16(a0.x, a0.y);  af.u4.y = pack_bf16(a0.z, a0.w);
            af.u4.z = pack_bf16(a1.x, a1.y);  af.u4.w = pack_bf16(a1.z, a1.w);
#pragma unroll
            for (int t = 0; t < 8; ++t) {
                union { short8 s8; uint4 u4; } bf;
                bf.u4 = *(const uint4*)&swB[((kc * 8 + t) * 64 + l) * 8];
                acc[t] = __builtin_amdgcn_mfma_f32_16x16x32_bf16(af.s8, bf.s8, acc[t], 0, 0, 0);
            }
        }

        // epilogue: D -> LDS (reuse swB) -> coalesced global
        __syncthreads();
        unsigned short* sc = swB;  // 64 nodes x 128 feats bf16 = 16 KB
#pragma unroll
        for (int t = 0; t < 8; ++t) {
#pragma unroll
            for (int r = 0; r < 4; ++r) {
                int ml = wv * 16 + q * 4 + r;
                int f  = t * 16 + m;
                sc[ml * FH + f] = bf16_1(acc[t][r]);
            }
        }
        __syncthreads();
        const uint4* s4 = (const uint4*)sc;
#pragma unroll
        for (int i = 0; i < 4; ++i) {
            int u  = tid + i * 256;
            int nl = u >> 4;
            int ng = gblk * 64 + nl;
            if (ng < NN)
                *((uint4*)h2 + (size_t)ng * 16 + (u & 15)) = s4[u];
        }
    } else {
        // bucket half: 4 edges/thread, separated phases.
        const int bidx = blockIdx.x >> 1;             // 0..781
        const int e0 = bidx * 1024 + tid;
        int                col[4];
        unsigned int       ent[4];
        unsigned long long add[4];
        int                ok[4];
#pragma unroll
        for (int k = 0; k < 4; ++k) {
            int e = e0 + k * 256;
            ok[k] = (e < NE);
            int ee = ok[k] ? e : 0;
            int row = ei[ee];
            col[k] = ei[NE + ee];
            float wv2 = ew[ee];
            ent[k] = ((unsigned int)row << 16) | __float2uint_rn(wv2 * EWS);
            add[k] = (1ULL << 32) | (unsigned long long)__float2uint_rn(wv2 * FXS);
        }
        int slot[4];
#pragma unroll
        for (int k = 0; k < 4; ++k)
            slot[k] = ok[k] ? (int)(atomicAdd(&packed[col[k]], add[k]) >> 32) : 0;
#pragma unroll
        for (int k = 0; k < 4; ++k)
            if (ok[k]) bucket[(size_t)col[k] * CAP + slot[k]] = ent[k];
    }
}

// ---------------------------------------------------------------------------
// K2: dinv table (per-SOURCE lookups in gather want a flat L2-resident
// table; r14's per-edge on-the-fly rsqrt lengthened the dependent chain
// and cost ~8 us). 50k threads, ~3 us.
// ---------------------------------------------------------------------------
__global__ __launch_bounds__(256) void k_dinv(const unsigned long long* __restrict__ packed,
                                              float* __restrict__ dinv) {
    int i = blockIdx.x * 256 + threadIdx.x;
    if (i < NN) {
        unsigned int lo = (unsigned int)(packed[i] & 0xffffffffu);
        dinv[i] = rsqrtf((float)lo * IFXS + 1.0f);  // +1 = self loop
    }
}

// ---------------------------------------------------------------------------
// K3: persistent gather-aggregate + fused BN-stats. Node's own dvn comes
// from packed[n] (c and deg in ONE 8-byte load, one rsqrt per node);
// per-source dinv from the table.
// ---------------------------------------------------------------------------
__global__ __launch_bounds__(256) void k_gather(const unsigned int* __restrict__ h2,
                                                const float* __restrict__ dinv,
                                                const unsigned long long* __restrict__ packed,
                                                const unsigned int* __restrict__ bucket,
                                                const float* __restrict__ conv_b,
                                                unsigned int* __restrict__ agg2,
                                                float* __restrict__ partial) {
    const int lane = threadIdx.x & 63;
    const int wv   = threadIdx.x >> 6;
    float2 bv = *(const float2*)(conv_b + lane * 2);

    float sa = 0.f, sb = 0.f, sa2 = 0.f, sb2 = 0.f;

    for (int n = blockIdx.x * 4 + wv; n < NN; n += GATHER_BLKS * 4) {
        unsigned long long pk = packed[n];
        int c = (int)(pk >> 32);
        float dvn = rsqrtf((float)(unsigned int)(pk & 0xffffffffu) * IFXS + 1.0f);

        unsigned int hself = h2[(size_t)n * 64 + lane];
        float ax = bf16_lo(hself) * dvn;
        float ay = bf16_hi(hself) * dvn;

        const unsigned int* bkt = bucket + (size_t)n * CAP;
        int j = 0;
        for (; j + 8 <= c; j += 8) {
            uint4 b0 = *(const uint4*)(bkt + j);
            uint4 b1 = *(const uint4*)(bkt + j + 4);
            unsigned int u[8] = {b0.x, b0.y, b0.z, b0.w, b1.x, b1.y, b1.z, b1.w};
            float t[8];
            unsigned int q[8];
#pragma unroll
            for (int r = 0; r < 8; ++r) {
                int s = u[r] >> 16;
                t[r] = dinv[s] * (float)(u[r] & 0xffffu) * IEWS;
                q[r] = h2[(size_t)s * 64 + lane];
            }
#pragma unroll
            for (int r = 0; r < 8; ++r) {
                ax = fmaf(bf16_lo(q[r]), t[r], ax);
                ay = fmaf(bf16_hi(q[r]), t[r], ay);
            }
        }
        if (j + 4 <= c) {
            uint4 b0 = *(const uint4*)(bkt + j);
            unsigned int u[4] = {b0.x, b0.y, b0.z, b0.w};
#pragma unroll
            for (int r = 0; r < 4; ++r) {
                int s = u[r] >> 16;
                float t = dinv[s] * (float)(u[r] & 0xffffu) * IEWS;
                unsigned int q = h2[(size_t)s * 64 + lane];
                ax = fmaf(bf16_lo(q), t, ax);
                ay = fmaf(bf16_hi(q), t, ay);
            }
            j += 4;
        }
        for (; j < c; ++j) {
            unsigned int u0 = bkt[j];
            int s0 = u0 >> 16;
            float t0 = dinv[s0] * (float)(u0 & 0xffffu) * IEWS;
            unsigned int q0 = h2[(size_t)s0 * 64 + lane];
            ax = fmaf(bf16_lo(q0), t0, ax);  ay = fmaf(bf16_hi(q0), t0, ay);
        }

        float ox = fmaxf(fmaf(dvn, ax, bv.x), 0.f);
        float oy = fmaxf(fmaf(dvn, ay, bv.y), 0.f);
        agg2[(size_t)n * 64 + lane] = pack_bf16(ox, oy);

        sa += ox;  sa2 = fmaf(ox, ox, sa2);
        sb += oy;  sb2 = fmaf(oy, oy, sb2);
    }

    // block-level stats reduce: partial[b][0..127]=sum, [128..255]=sumsq
    __shared__ float red[256];
    float vals[4] = {sa, sb, sa2, sb2};
    float* pb = partial + (size_t)blockIdx.x * 256;
#pragma unroll
    for (int r = 0; r < 4; ++r) {
        red[threadIdx.x] = vals[r];
        __syncthreads();
        if (wv == 0) {
            float t = red[lane] + red[lane + 64] + red[lane + 128] + red[lane + 192];
            pb[((r < 2) ? 0 : FH) + 2 * lane + (r & 1)] = t;
        }
        __syncthreads();
    }
}

// ---------------------------------------------------------------------------
// K4: stage-2 stats reduction: 8 blocks, each sums 256 partial rows.
// ---------------------------------------------------------------------------
__global__ __launch_bounds__(256) void k_red(const float* __restrict__ partial,
                                             float* __restrict__ stage2) {
    int i = threadIdx.x;
    const float* base = partial + (size_t)blockIdx.x * 256 * 256;
    float acc = 0.f;
    for (int j = 0; j < 256; ++j) acc += base[j * 256 + i];
    stage2[blockIdx.x * 256 + i] = acc;
}

// ---------------------------------------------------------------------------
// K5: final stats reduce + fold BN affine into the linear.
// ---------------------------------------------------------------------------
__global__ void k_prep(const float* __restrict__ stage2,
                       const float* __restrict__ gamma,
                       const float* __restrict__ beta,
                       const float* __restrict__ lin_w,
                       const float* __restrict__ lin_b,
                       float* __restrict__ prep) {
    __shared__ float ssum[256];
    __shared__ float red[3 * FH];
    int i = threadIdx.x;  // 256 threads
    float acc = 0.f;
#pragma unroll
    for (int r = 0; r < RED_BLKS; ++r) acc += stage2[r * 256 + i];
    ssum[i] = acc;
    __syncthreads();
    if (i < FH) {
        float mean = ssum[i] * (1.0f / NN);
        float var  = ssum[FH + i] * (1.0f / NN) - mean * mean;
        float inv  = rsqrtf(var + BN_EPS);
        float sc   = inv * gamma[i];
        float sh   = fmaf(-mean, sc, beta[i]);
#pragma unroll
        for (int o = 0; o < NOUT; ++o) {
            float lw = lin_w[i * NOUT + o];
            prep[i * NOUT + o] = sc * lw;
            red[o * FH + i]    = sh * lw;
        }
    }
    __syncthreads();
    if (i < NOUT) {
        float s = lin_b[i];
        for (int f = 0; f < FH; ++f) s += red[i * FH + f];
        prep[3 * FH + i] = s;
    }
}

// ---------------------------------------------------------------------------
// K6: out[n][o] = sum_f agg[n][f] * wmod[f][o] + bias_out[o]
// ---------------------------------------------------------------------------
__global__ __launch_bounds__(256) void k_final(const unsigned int* __restrict__ agg2,
                                               const float* __restrict__ prep,
                                               float* __restrict__ out) {
    int n = blockIdx.x * 4 + (threadIdx.x >> 6);
    int lane = threadIdx.x & 63;
    int f0 = lane * 2, f1 = lane * 2 + 1;

    unsigned int v = agg2[(size_t)n * 64 + lane];
    float vx = bf16_lo(v), vy = bf16_hi(v);

    float o0 = vx * prep[f0 * NOUT + 0] + vy * prep[f1 * NOUT + 0];
    float o1 = vx * prep[f0 * NOUT + 1] + vy * prep[f1 * NOUT + 1];
    float o2 = vx * prep[f0 * NOUT + 2] + vy * prep[f1 * NOUT + 2];

#pragma unroll
    for (int off = 32; off > 0; off >>= 1) {
        o0 += __shfl_down(o0, off, 64);
        o1 += __shfl_down(o1, off, 64);
        o2 += __shfl_down(o2, off, 64);
    }
    if (lane == 0) {
        out[n * NOUT + 0] = o0 + prep[3 * FH + 0];
        out[n * NOUT + 1] = o1 + prep[3 * FH + 1];
        out[n * NOUT + 2] = o2 + prep[3 * FH + 2];
    }
}

// ---------------------------------------------------------------------------
extern "C" void kernel_launch(void* const* d_in, const int* in_sizes, int n_in,
                              void* d_out, int out_size, void* d_ws, size_t ws_size,
                              hipStream_t stream) {
    const float* x      = (const float*)d_in[0];
    const int*   ei     = (const int*)d_in[1];   // [2][NE] int32
    const float* ew     = (const float*)d_in[2];
    const float* conv_w = (const float*)d_in[3];
    const float* conv_b = (const float*)d_in[4];
    const float* gamma  = (const float*)d_in[5];
    const float* beta   = (const float*)d_in[6];
    const float* lin_w  = (const float*)d_in[7];
    const float* lin_b  = (const float*)d_in[8];
    float* out = (float*)d_out;
    float* ws  = (float*)d_ws;

    unsigned int*       h2      = (unsigned int*)(ws + WS_H2);
    unsigned int*       agg2    = (unsigned int*)(ws + WS_AGG2);
    unsigned int*       bucket  = (unsigned int*)(ws + WS_BUCKET);
    unsigned long long* packed  = (unsigned long long*)(ws + WS_PACKED);
    float*              dinv    = ws + WS_DINV;
    float*              partial = ws + WS_PARTIAL;
    float*              stage2  = ws + WS_STAGE2;
    float*              prep    = ws + WS_PREP;

    // ws is poisoned 0xAA before every launch — zero the atomic accumulator.
    hipMemsetAsync(packed, 0, (size_t)NN * sizeof(unsigned long long), stream);

    k_gemm_bucket<<<FUSED_BLKS, 256, 0, stream>>>(x, conv_w, h2, ei, ew, packed, bucket);
    k_dinv  <<<DINV_BLKS,   256, 0, stream>>>(packed, dinv);
    k_gather<<<GATHER_BLKS, 256, 0, stream>>>(h2, dinv, packed, bucket, conv_b, agg2, partial);
    k_red   <<<RED_BLKS,    256, 0, stream>>>(partial, stage2);
    k_prep  <<<1,           256, 0, stream>>>(stage2, gamma, beta, lin_w, lin_b, prep);
    k_final <<<NN / 4,      256, 0, stream>>>(agg2, prep, out);
}